// Round 3
// baseline (191.611 us; speedup 1.0000x reference)
//
#include <hip/hip_runtime.h>
#include <hip/hip_bf16.h>
#include <math.h>

#define BATCH 32
#define T 1024
#define F 768

// Workspace layout:
//   [0, 256)      : unsigned long long best[32]   (packed argmax, memset to 0)
//   [256, 768)    : float accum[32][4]            (den, n0, n1, pad; memset to 0)
//   [4096, 528384): float4 stats[32768]           (p, y0, y1, inv_norm) per token

// ---------------------------------------------------------------------------
// K1: per-token stats + fused per-batch argmax.
// grid = 1024 blocks (32 per batch), 256 thr = 4 waves, 32 tokens/block.
// Only l0-l1 is needed => accumulate v.(w0-w1): 4-value butterfly, 16 FMA/j.
// ---------------------------------------------------------------------------
__global__ __launch_bounds__(256) void k1_token_stats(
    const float* __restrict__ x, const float* __restrict__ fc_w,
    const float* __restrict__ fc_b, const float* __restrict__ fc_final_w,
    float4* __restrict__ stats, unsigned long long* __restrict__ best)
{
    const int wave = threadIdx.x >> 6;
    const int lane = threadIdx.x & 63;
    const int b     = blockIdx.x >> 5;          // 32 blocks per batch
    const int tbase = (blockIdx.x & 31) * 32;   // token base within batch

    // hoist weights to registers; fc_w rows collapse to their difference
    float4 wd[3], f0[3], f1[3];
    #pragma unroll
    for (int j = 0; j < 3; ++j) {
        const int off = j * 256 + lane * 4;
        float4 a = *(const float4*)(fc_w + off);
        float4 c = *(const float4*)(fc_w + F + off);
        wd[j] = make_float4(a.x - c.x, a.y - c.y, a.z - c.z, a.w - c.w);
        f0[j] = *(const float4*)(fc_final_w + off);
        f1[j] = *(const float4*)(fc_final_w + F + off);
    }
    const float bias01 = fc_b[0] - fc_b[1];

    float bp = -1.f; int bidx = 0;              // wave-local argmax (same in all lanes)
    #pragma unroll
    for (int it = 0; it < 8; ++it) {
        const int t = tbase + it * 4 + wave;    // block reads 4 consecutive tokens/iter
        const float* tok = x + ((size_t)b * T + t) * F;
        float asq = 0.f, da = 0.f, af0 = 0.f, af1 = 0.f;
        #pragma unroll
        for (int j = 0; j < 3; ++j) {
            float4 v = *(const float4*)(tok + j * 256 + lane * 4);
            asq += v.x*v.x       + v.y*v.y       + v.z*v.z       + v.w*v.w;
            da  += v.x*wd[j].x + v.y*wd[j].y + v.z*wd[j].z + v.w*wd[j].w;
            af0 += v.x*f0[j].x + v.y*f0[j].y + v.z*f0[j].z + v.w*f0[j].w;
            af1 += v.x*f1[j].x + v.y*f1[j].y + v.z*f1[j].z + v.w*f1[j].w;
        }
        #pragma unroll
        for (int d = 32; d > 0; d >>= 1) {
            asq += __shfl_xor(asq, d);
            da  += __shfl_xor(da,  d);
            af0 += __shfl_xor(af0, d);
            af1 += __shfl_xor(af1, d);
        }
        const float p = 1.f / (1.f + expf(da + bias01));  // softmax(logits)[1]
        if (lane == 0)
            stats[(size_t)b * T + t] = make_float4(p, af0, af1, 1.f / sqrtf(asq));
        if (p > bp) { bp = p; bidx = t; }       // strict > keeps first max in-wave
    }

    // block argmax then one packed atomicMax per block (32 per target address)
    __shared__ float sp[4]; __shared__ int si[4];
    if (lane == 0) { sp[wave] = bp; si[wave] = bidx; }
    __syncthreads();
    if (threadIdx.x == 0) {
        float P = sp[0]; int I = si[0];
        for (int w = 1; w < 4; ++w)
            if (sp[w] > P || (sp[w] == P && si[w] < I)) { P = sp[w]; I = si[w]; }
        // p > 0 => float bits order-preserving; low word 0xFFFFFFFF-idx => first-max ties
        const unsigned long long pk =
            ((unsigned long long)__float_as_uint(P) << 32) |
            (unsigned long long)(0xFFFFFFFFu - (unsigned)I);
        atomicMax(&best[b], pk);
    }
}

// ---------------------------------------------------------------------------
// K3: weighted accumulation. s = cosine in [-1,1] => exp(s) safe, softmax
// max-shift cancels in the renormalization => plain sums, no online max.
// grid = 2048 blocks (64 per batch), 16 tokens/block => 32 waves/CU.
// ---------------------------------------------------------------------------
__global__ __launch_bounds__(256) void k3_attn_row(
    const float* __restrict__ x, const float4* __restrict__ stats,
    const unsigned long long* __restrict__ best, float* __restrict__ accum)
{
    const int b     = blockIdx.x >> 6;          // 64 blocks per batch
    const int tbase = (blockIdx.x & 63) * 16;
    const int wave = threadIdx.x >> 6;
    const int lane = threadIdx.x & 63;

    const int idx = (int)(0xFFFFFFFFu - (unsigned)(best[b] & 0xFFFFFFFFull));

    __shared__ float q[F];
    const float4 qs = stats[(size_t)b * T + idx];
    const float* qg = x + ((size_t)b * T + idx) * F;
    for (int i = threadIdx.x; i < F; i += 256) q[i] = qg[i] * qs.w;  // pre-scale by 1/||q||
    __syncthreads();

    float den = 0.f, n0 = 0.f, n1 = 0.f;        // identical in all lanes (post-butterfly)
    #pragma unroll
    for (int it = 0; it < 4; ++it) {
        const int t = tbase + it * 4 + wave;
        const float* tok = x + ((size_t)b * T + t) * F;
        const float4 st = stats[(size_t)b * T + t];   // (p, y0, y1, inv_norm) broadcast
        float acc = 0.f;
        #pragma unroll
        for (int j = 0; j < 3; ++j) {
            const int off = j * 256 + lane * 4;
            float4 v  = *(const float4*)(tok + off);
            float4 qq = *(const float4*)(&q[off]);
            acc += v.x*qq.x + v.y*qq.y + v.z*qq.z + v.w*qq.w;
        }
        #pragma unroll
        for (int d = 32; d > 0; d >>= 1) acc += __shfl_xor(acc, d);
        const float w = expf(acc * st.w) * st.x;      // exp(cos) * p
        den += w; n0 += w * st.y; n1 += w * st.z;
    }

    __shared__ float red[4][3];
    if (lane == 0) { red[wave][0] = den; red[wave][1] = n0; red[wave][2] = n1; }
    __syncthreads();
    if (threadIdx.x == 0) {
        float D = 0.f, N0 = 0.f, N1 = 0.f;
        for (int w = 0; w < 4; ++w) { D += red[w][0]; N0 += red[w][1]; N1 += red[w][2]; }
        atomicAdd(&accum[b * 4 + 0], D);
        atomicAdd(&accum[b * 4 + 1], N0);
        atomicAdd(&accum[b * 4 + 2], N1);
    }
}

// ---------------------------------------------------------------------------
// K4: trivial finalize, one block.
// ---------------------------------------------------------------------------
__global__ __launch_bounds__(64) void k4_finalize(
    const float* __restrict__ accum, const float* __restrict__ fc_final_b,
    float* __restrict__ out)
{
    const int b = threadIdx.x;
    if (b < BATCH) {
        const float D = accum[b * 4], N0 = accum[b * 4 + 1], N1 = accum[b * 4 + 2];
        out[b * 2 + 0] = N0 / D + fc_final_b[0];
        out[b * 2 + 1] = N1 / D + fc_final_b[1];
    }
}

extern "C" void kernel_launch(void* const* d_in, const int* in_sizes, int n_in,
                              void* d_out, int out_size, void* d_ws, size_t ws_size,
                              hipStream_t stream) {
    const float* x          = (const float*)d_in[0];
    const float* fc_w       = (const float*)d_in[1];
    const float* fc_b       = (const float*)d_in[2];
    const float* fc_final_w = (const float*)d_in[3];
    const float* fc_final_b = (const float*)d_in[4];
    float* out = (float*)d_out;

    char* ws = (char*)d_ws;
    unsigned long long* best = (unsigned long long*)ws;       // 256 B
    float*  accum = (float*)(ws + 256);                       // 512 B
    float4* stats = (float4*)(ws + 4096);                     // 512 KB

    hipMemsetAsync(ws, 0, 768, stream);                       // zero best + accum
    k1_token_stats<<<dim3(BATCH * 32), 256, 0, stream>>>(
        x, fc_w, fc_b, fc_final_w, stats, best);
    k3_attn_row<<<dim3(BATCH * 64), 256, 0, stream>>>(x, stats, best, accum);
    k4_finalize<<<dim3(1), 64, 0, stream>>>(accum, fc_final_b, out);
}

// Round 4
// 171.083 us; speedup vs baseline: 1.1200x; 1.1200x over previous
//
#include <hip/hip_runtime.h>
#include <hip/hip_bf16.h>
#include <math.h>

#define BATCH 32
#define T 1024
#define F 768

// Workspace layout (NO zero-init required anywhere):
//   [0, 8192)        : u64  best[1024]      one packed (p,idx) candidate per K1 block
//   [8192, 40960)    : f32  part[32][64][4] (den, n0, n1, pad) per K3 block
//   [65536, 589824)  : f32x4 stats[32768]   (p, y0, y1, inv_norm) per token

// ---------------------------------------------------------------------------
// K1: per-token stats + per-block argmax candidate (no atomics).
// grid = 1024 blocks (32/batch), 4 waves, 32 tokens/block.
// ---------------------------------------------------------------------------
__global__ __launch_bounds__(256) void k1_token_stats(
    const float* __restrict__ x, const float* __restrict__ fc_w,
    const float* __restrict__ fc_b, const float* __restrict__ fc_final_w,
    float4* __restrict__ stats, unsigned long long* __restrict__ best)
{
    const int wave = threadIdx.x >> 6;
    const int lane = threadIdx.x & 63;
    const int b     = blockIdx.x >> 5;          // 32 blocks per batch
    const int tbase = (blockIdx.x & 31) * 32;   // token base within batch

    // hoist weights to registers; fc_w rows collapse to their difference
    float4 wd[3], f0[3], f1[3];
    #pragma unroll
    for (int j = 0; j < 3; ++j) {
        const int off = j * 256 + lane * 4;
        float4 a = *(const float4*)(fc_w + off);
        float4 c = *(const float4*)(fc_w + F + off);
        wd[j] = make_float4(a.x - c.x, a.y - c.y, a.z - c.z, a.w - c.w);
        f0[j] = *(const float4*)(fc_final_w + off);
        f1[j] = *(const float4*)(fc_final_w + F + off);
    }
    const float bias01 = fc_b[0] - fc_b[1];

    float bp = -1.f; int bidx = 0;              // wave-local argmax (same in all lanes)
    #pragma unroll
    for (int it = 0; it < 8; ++it) {
        const int t = tbase + it * 4 + wave;    // block reads 4 consecutive tokens/iter
        const float* tok = x + ((size_t)b * T + t) * F;
        float asq = 0.f, da = 0.f, af0 = 0.f, af1 = 0.f;
        #pragma unroll
        for (int j = 0; j < 3; ++j) {
            float4 v = *(const float4*)(tok + j * 256 + lane * 4);
            asq += v.x*v.x     + v.y*v.y     + v.z*v.z     + v.w*v.w;
            da  += v.x*wd[j].x + v.y*wd[j].y + v.z*wd[j].z + v.w*wd[j].w;
            af0 += v.x*f0[j].x + v.y*f0[j].y + v.z*f0[j].z + v.w*f0[j].w;
            af1 += v.x*f1[j].x + v.y*f1[j].y + v.z*f1[j].z + v.w*f1[j].w;
        }
        #pragma unroll
        for (int d = 32; d > 0; d >>= 1) {
            asq += __shfl_xor(asq, d);
            da  += __shfl_xor(da,  d);
            af0 += __shfl_xor(af0, d);
            af1 += __shfl_xor(af1, d);
        }
        const float p = 1.f / (1.f + expf(da + bias01));  // softmax(logits)[1]
        if (lane == 0)
            stats[(size_t)b * T + t] = make_float4(p, af0, af1, 1.f / sqrtf(asq));
        if (p > bp) { bp = p; bidx = t; }       // strict > keeps first max in-wave
    }

    // block candidate -> distinct slot; packed so plain u64 max == numpy argmax:
    // p > 0 => float bits order-preserving; low word 0xFFFFFFFF-idx => first-max ties
    __shared__ float sp[4]; __shared__ int si[4];
    if (lane == 0) { sp[wave] = bp; si[wave] = bidx; }
    __syncthreads();
    if (threadIdx.x == 0) {
        float P = sp[0]; int I = si[0];
        for (int w = 1; w < 4; ++w)
            if (sp[w] > P || (sp[w] == P && si[w] < I)) { P = sp[w]; I = si[w]; }
        best[blockIdx.x] =
            ((unsigned long long)__float_as_uint(P) << 32) |
            (unsigned long long)(0xFFFFFFFFu - (unsigned)I);
    }
}

// ---------------------------------------------------------------------------
// K3: weighted accumulation. s = cosine in [-1,1] => exp(s) safe; softmax
// max-shift cancels algebraically => plain sums.
// q lives in 3 float4 REGISTERS per lane (each lane only needs its own 12
// floats) — no LDS, no __syncthreads in the hot path.
// grid = 2048 blocks (64/batch), 16 tokens/block.
// ---------------------------------------------------------------------------
__global__ __launch_bounds__(256) void k3_attn_row(
    const float* __restrict__ x, const float4* __restrict__ stats,
    const unsigned long long* __restrict__ best, float4* __restrict__ part)
{
    const int b     = blockIdx.x >> 6;          // 64 blocks per batch
    const int tbase = (blockIdx.x & 63) * 16;
    const int wave = threadIdx.x >> 6;
    const int lane = threadIdx.x & 63;

    // reduce the 32 per-block argmax candidates: u64 max butterfly (all waves
    // redundantly; lanes >=32 contribute 0 which never wins since p>0)
    unsigned long long pk = (lane < 32) ? best[b * 32 + lane] : 0ull;
    #pragma unroll
    for (int d = 32; d > 0; d >>= 1) {
        const unsigned long long o = __shfl_xor(pk, d);
        pk = o > pk ? o : pk;
    }
    const int idx = (int)(0xFFFFFFFFu - (unsigned)(pk & 0xFFFFFFFFull));

    // q fragment in registers, pre-scaled by 1/||q||
    const float4 qs = stats[(size_t)b * T + idx];
    const float* qg = x + ((size_t)b * T + idx) * F;
    float4 q[3];
    #pragma unroll
    for (int j = 0; j < 3; ++j) {
        float4 v = *(const float4*)(qg + j * 256 + lane * 4);
        q[j] = make_float4(v.x * qs.w, v.y * qs.w, v.z * qs.w, v.w * qs.w);
    }

    float den = 0.f, n0 = 0.f, n1 = 0.f;
    #pragma unroll
    for (int it = 0; it < 4; ++it) {
        const int t = tbase + it * 4 + wave;
        const float* tok = x + ((size_t)b * T + t) * F;
        const float4 st = stats[(size_t)b * T + t];   // (p, y0, y1, inv_norm)
        float acc = 0.f;
        #pragma unroll
        for (int j = 0; j < 3; ++j) {
            float4 v = *(const float4*)(tok + j * 256 + lane * 4);
            acc += v.x*q[j].x + v.y*q[j].y + v.z*q[j].z + v.w*q[j].w;
        }
        #pragma unroll
        for (int d = 32; d > 0; d >>= 1) acc += __shfl_xor(acc, d);
        const float w = expf(acc * st.w) * st.x;      // exp(cos) * p
        den += w; n0 += w * st.y; n1 += w * st.z;
    }

    __shared__ float red[4][3];
    if (lane == 0) { red[wave][0] = den; red[wave][1] = n0; red[wave][2] = n1; }
    __syncthreads();
    if (threadIdx.x == 0) {
        float D = 0.f, N0 = 0.f, N1 = 0.f;
        for (int w = 0; w < 4; ++w) { D += red[w][0]; N0 += red[w][1]; N1 += red[w][2]; }
        part[(size_t)b * 64 + (blockIdx.x & 63)] = make_float4(D, N0, N1, 0.f);
    }
}

// ---------------------------------------------------------------------------
// K4: one wave per batch reduces 64 partials -> out[B,2]
// ---------------------------------------------------------------------------
__global__ __launch_bounds__(64) void k4_finalize(
    const float4* __restrict__ part, const float* __restrict__ fc_final_b,
    float* __restrict__ out)
{
    const int b = blockIdx.x;
    const int lane = threadIdx.x;
    float4 v = part[(size_t)b * 64 + lane];
    float D = v.x, N0 = v.y, N1 = v.z;
    #pragma unroll
    for (int d = 32; d > 0; d >>= 1) {
        D  += __shfl_xor(D,  d);
        N0 += __shfl_xor(N0, d);
        N1 += __shfl_xor(N1, d);
    }
    if (lane == 0) {
        out[b * 2 + 0] = N0 / D + fc_final_b[0];
        out[b * 2 + 1] = N1 / D + fc_final_b[1];
    }
}

extern "C" void kernel_launch(void* const* d_in, const int* in_sizes, int n_in,
                              void* d_out, int out_size, void* d_ws, size_t ws_size,
                              hipStream_t stream) {
    const float* x          = (const float*)d_in[0];
    const float* fc_w       = (const float*)d_in[1];
    const float* fc_b       = (const float*)d_in[2];
    const float* fc_final_w = (const float*)d_in[3];
    const float* fc_final_b = (const float*)d_in[4];
    float* out = (float*)d_out;

    char* ws = (char*)d_ws;
    unsigned long long* best = (unsigned long long*)ws;       // 8 KB
    float4* part  = (float4*)(ws + 8192);                     // 32 KB
    float4* stats = (float4*)(ws + 65536);                    // 512 KB

    k1_token_stats<<<dim3(BATCH * 32), 256, 0, stream>>>(
        x, fc_w, fc_b, fc_final_w, stats, best);
    k3_attn_row<<<dim3(BATCH * 64), 256, 0, stream>>>(x, stats, best, part);
    k4_finalize<<<dim3(BATCH), 64, 0, stream>>>(part, fc_final_b, out);
}